// Round 2
// baseline (223.199 us; speedup 1.0000x reference)
//
#include <hip/hip_runtime.h>

#define W 320
#define H 96
#define FS 96
#define BS 8
#define NPLANES 9      // 1 + 2*4 levels
#define CH 24          // channels staged per LDS stage
#define NSTAGES 4      // FS / CH
#define PADW 328       // 4 guard + 320 + 4 guard
#define NTHREADS 192   // 3 waves; 160 active in compute (VX=2 over w=320)

__global__ __launch_bounds__(NTHREADS, 2)
void cost_volume_kernel(const float* __restrict__ f1,
                        const float* __restrict__ f2,
                        float* __restrict__ out)
{
    __shared__ float sh[CH * PADW];  // 31,488 B -> 3 blocks/CU (94.5 KB)

    const int t   = threadIdx.x;
    const int row = blockIdx.x;      // 0..767 = (b, y)
    const int b   = row / H;
    const int y   = row % H;

    // Zero the +-4 guards once (disjoint from staged region, write-once).
    {
        const int c = t >> 3;
        const int g = t & 7;
        sh[c * PADW + (g < 4 ? g : 320 + g)] = 0.0f;
    }

    const float* f1row = f1 + ((size_t)(b * FS) * H + y) * W;
    const float* f2row = f2 + ((size_t)(b * FS) * H + y) * W;

    float acc0[NPLANES], acc1[NPLANES];
#pragma unroll
    for (int p = 0; p < NPLANES; ++p) { acc0[p] = 0.f; acc1[p] = 0.f; }

    const int xi = t;        // compute lane: xi < 160
    const int x0 = 2 * xi;   // even -> 8B-aligned LDS window reads

    const int sc = t >> 3;   // staged channel owned by this thread
    const int su = t & 7;    // sub-lane within channel row
    const float* f2c0 = f2row + (size_t)sc * (H * W);

    // ---- software pipeline: stage-0 f2 quads prefetched into registers ----
    float4 st[10];
#pragma unroll
    for (int k = 0; k < 10; ++k)
        st[k] = *(const float4*)(f2c0 + 4 * (su + 8 * k));

    for (int s = 0; s < NSTAGES; ++s) {
        __syncthreads();     // previous stage's readers done
#pragma unroll
        for (int k = 0; k < 10; ++k)
            *(float4*)(&sh[sc * PADW + 4 + 4 * (su + 8 * k)]) = st[k];
        __syncthreads();

        // Prefetch ALL f1 values for this stage: 24 independent loads in flight.
        float2 a[CH];
        if (xi < 160) {
#pragma unroll
            for (int c = 0; c < CH; ++c)
                a[c] = *(const float2*)(f1row + (size_t)(s * CH + c) * (H * W) + x0);
        }

        // Prefetch NEXT stage's f2 quads into registers (overlaps compute).
        if (s + 1 < NSTAGES) {
            const float* f2c = f2c0 + (size_t)((s + 1) * CH) * (H * W);
#pragma unroll
            for (int k = 0; k < 10; ++k)
                st[k] = *(const float4*)(f2c + 4 * (su + 8 * k));
        }

        // ---- compute: 24 channels x 18 FMAs, window from LDS ----
        if (xi < 160) {
#pragma unroll
            for (int c = 0; c < CH; ++c) {
                float wv[10];
#pragma unroll
                for (int k = 0; k < 5; ++k) {
                    const float2 v = *(const float2*)(&sh[c * PADW + x0 + 2 * k]);
                    wv[2 * k]     = v.x;
                    wv[2 * k + 1] = v.y;
                }
                // plane p <-> shift i = p-4; f2 col = x - i = x + 4 - p
#pragma unroll
                for (int p = 0; p < NPLANES; ++p) {
                    acc0[p] = fmaf(a[c].x, wv[8 - p], acc0[p]);
                    acc1[p] = fmaf(a[c].y, wv[9 - p], acc1[p]);
                }
            }
        }
        // no trailing barrier: next iteration's first __syncthreads covers it
    }

    if (xi < 160) {
        const float scale = 1.0f / (float)FS;
#pragma unroll
        for (int p = 0; p < NPLANES; ++p) {
            float2 o;
            o.x = acc0[p] * scale;
            o.y = acc1[p] * scale;
            *(float2*)(out + (((size_t)(b * NPLANES + p)) * H + y) * W + x0) = o;
        }
    }
}

extern "C" void kernel_launch(void* const* d_in, const int* in_sizes, int n_in,
                              void* d_out, int out_size, void* d_ws, size_t ws_size,
                              hipStream_t stream) {
    (void)in_sizes; (void)n_in; (void)d_ws; (void)ws_size; (void)out_size;
    const float* f1 = (const float*)d_in[0];
    const float* f2 = (const float*)d_in[1];
    float* out = (float*)d_out;

    dim3 grid(BS * H);        // 768 blocks = 3 per CU exactly
    dim3 block(NTHREADS);
    cost_volume_kernel<<<grid, block, 0, stream>>>(f1, f2, out);
}

// Round 3
// 222.974 us; speedup vs baseline: 1.0010x; 1.0010x over previous
//
#include <hip/hip_runtime.h>

#define W 320
#define H 96
#define FS 96
#define BS 8
#define HW (H * W)
#define NPLANES 9      // 1 + 2*4 levels
#define CH 16          // channels staged per LDS stage
#define CHB 48         // channels per block (FS/2)
#define NSTAGES 3      // CHB / CH
#define PADW 328       // 4 guard + 320 + 4 guard
#define NTHREADS 320   // 5 waves; every thread computes exactly 1 column

__global__ __launch_bounds__(NTHREADS, 8)   // force VGPR<=64 -> 30 waves/CU
void cost_volume_kernel(const float* __restrict__ f1,
                        const float* __restrict__ f2,
                        float* __restrict__ out)
{
    __shared__ float sh[CH * PADW];  // 20,992 B -> 6 blocks/CU = 126 KB

    const int t   = threadIdx.x;
    const int bid = blockIdx.x;
    const int row = bid >> 1;        // (b, y)
    const int hh  = bid & 1;         // which 48-channel half
    const int b   = row / H;
    const int y   = row % H;
    const int ch0 = hh * CHB;

    // Zero the +-4 per-channel guards once (never overwritten by staging).
    if (t < CH * 8) {
        const int c = t >> 3, g = t & 7;
        sh[c * PADW + (g < 4 ? g : 320 + g)] = 0.0f;
    }

    const float* f1base = f1 + (((size_t)b * FS) * H + y) * W;
    const float* f2base = f2 + (((size_t)b * FS) * H + y) * W;

    float acc[NPLANES];
#pragma unroll
    for (int p = 0; p < NPLANES; ++p) acc[p] = 0.0f;

    const int xi = t;                // column owned by this thread
    const int sc = t / 20;           // staged channel 0..15 (16 ch x 20 lanes)
    const int sp = t - sc * 20;      // quad slot 0..19 (80 quads per channel)

    // software pipeline: stage-0 f2 quads in registers (4 x float4 = 16 VGPR)
    float4 st[4];
    {
        const float* f2s = f2base + (size_t)(ch0 + sc) * HW;
#pragma unroll
        for (int k = 0; k < 4; ++k)
            st[k] = *(const float4*)(f2s + 4 * (sp + 20 * k));
    }

    for (int s = 0; s < NSTAGES; ++s) {
        __syncthreads();             // prev-stage readers done (covers guard init too)
#pragma unroll
        for (int k = 0; k < 4; ++k)
            *(float4*)(&sh[sc * PADW + 4 + 4 * (sp + 20 * k)]) = st[k];
        __syncthreads();

        // prefetch next stage's f2 quads (overlaps compute below)
        if (s + 1 < NSTAGES) {
            const float* f2s = f2base + (size_t)(ch0 + (s + 1) * CH + sc) * HW;
#pragma unroll
            for (int k = 0; k < 4; ++k)
                st[k] = *(const float4*)(f2s + 4 * (sp + 20 * k));
        }

        // compute: 16 channels in two 8-channel chunks (a[8] = 8 VGPR only)
        const float* f1s = f1base + (size_t)(ch0 + s * CH) * HW + xi;
#pragma unroll
        for (int cc = 0; cc < 2; ++cc) {
            float a[8];
#pragma unroll
            for (int j = 0; j < 8; ++j)
                a[j] = f1s[(size_t)(cc * 8 + j) * HW];
#pragma unroll
            for (int j = 0; j < 8; ++j) {
                const float* wp = &sh[(cc * 8 + j) * PADW + xi];
                // plane p <-> shift i=p-4; f2 col = x+4-p; staged at +4 offset
#pragma unroll
                for (int p = 0; p < NPLANES; ++p)
                    acc[p] = fmaf(a[j], wp[8 - p], acc[p]);
            }
        }
    }

    const float scale = 1.0f / (float)FS;
    float* orow = out + (((size_t)b * NPLANES) * H + y) * W + xi;
#pragma unroll
    for (int p = 0; p < NPLANES; ++p)
        atomicAdd(orow + (size_t)p * HW, acc[p] * scale);
}

extern "C" void kernel_launch(void* const* d_in, const int* in_sizes, int n_in,
                              void* d_out, int out_size, void* d_ws, size_t ws_size,
                              hipStream_t stream) {
    (void)in_sizes; (void)n_in; (void)d_ws; (void)ws_size;
    const float* f1 = (const float*)d_in[0];
    const float* f2 = (const float*)d_in[1];
    float* out = (float*)d_out;

    // Output is 0xAA-poisoned before every launch; atomics need zeros.
    hipMemsetAsync(d_out, 0, (size_t)out_size * sizeof(float), stream);

    dim3 grid(BS * H * 2);   // 1536 blocks = 6 per CU x 5 waves = 30 waves/CU
    dim3 block(NTHREADS);
    cost_volume_kernel<<<grid, block, 0, stream>>>(f1, f2, out);
}